// Round 24
// baseline (1140.317 us; speedup 1.0000x reference)
//
#include <hip/hip_runtime.h>
#include <hip/hip_bf16.h>
#include <cmath>

typedef __hip_bfloat16 bf16;
typedef __attribute__((ext_vector_type(8))) short short8;
typedef __attribute__((ext_vector_type(4))) float float4v;

__device__ __forceinline__ float b2f(bf16 v) { return __bfloat162float(v); }
__device__ __forceinline__ bf16  f2b(float v) { return __float2bfloat16(v); }
__device__ __forceinline__ float bfr(unsigned int u) { union { float f; unsigned int i; } c; c.i = u << 16; return c.f; }
__device__ __forceinline__ void ld4(const float* p, float* o) {
    float4 q = *(const float4*)p; o[0]=q.x; o[1]=q.y; o[2]=q.z; o[3]=q.w;
}
__device__ __forceinline__ void ld4(const bf16* p, float* o) {
    const uint2 q = *(const uint2*)p;
    o[0] = bfr(q.x & 0xffffu); o[1] = bfr(q.x >> 16);
    o[2] = bfr(q.y & 0xffffu); o[3] = bfr(q.y >> 16);
}
template <typename T>
__device__ __forceinline__ void ld8(const T* p, float* o) { ld4(p, o); ld4(p + 4, o + 4); }
__device__ __forceinline__ float ldv(const float* p) { return *p; }
__device__ __forceinline__ float ldv(const bf16* p)  { return b2f(*p); }
__device__ __forceinline__ void  stv(float* p, float v) { *p = v; }
__device__ __forceinline__ void  stv(bf16* p, float v)  { *p = f2b(v); }

__device__ __forceinline__ float siluf(float x) { return x / (1.f + expf(-x)); }
__device__ __forceinline__ float geluf(float x) { return 0.5f * x * (1.f + erff(x * 0.70710678118654752f)); }

// ---------------- fragment-offset helper ----------------
__device__ __forceinline__ int frag_off(int k, int n, int NT) {
    return ((k >> 5) * NT + (n >> 4)) * 512 + (((k >> 3) & 3) * 16 + (n & 15)) * 8 + (k & 7);
}

// ---------------- ONE merged weight-prep kernel (all 10 jobs) ----------------
__global__ __launch_bounds__(256) void k_prep_all(
    const float* __restrict__ moe_w1, const float* __restrict__ moe_w2,
    const float* __restrict__ fc1_w, const float* __restrict__ fc2_w,
    const float* __restrict__ proj_w, const float* __restrict__ w_1x1,
    const float* __restrict__ w_kxk, const float* __restrict__ w_fus,
    const float* __restrict__ qkv_w, const float* __restrict__ w_proj,
    bf16* __restrict__ wprep)
{
    const int idx = blockIdx.x * 256 + threadIdx.x;
    if (idx >= 1376256) return;
    int base, local;
    const float* src;
    if (idx < 147456)        { base = 0;       local = idx - base; src = moe_w1;
        int per = 36864, m = local / per, rem = local - m * per;
        wprep[base + m * per + frag_off(rem / 192, rem % 192, 12)] = f2b(src[local]); }
    else if (idx < 294912)   { base = 147456;  local = idx - base; src = moe_w2;
        int per = 36864, m = local / per, rem = local - m * per;
        wprep[base + m * per + frag_off(rem / 192, rem % 192, 12)] = f2b(src[local]); }
    else if (idx < 442368)   { base = 294912;  local = idx - base; src = fc1_w;
        int per = 73728, m = local / per, rem = local - m * per;
        wprep[base + m * per + frag_off(rem / 384, rem % 384, 24)] = f2b(src[local]); }
    else if (idx < 589824)   { base = 442368;  local = idx - base; src = fc2_w;
        int per = 73728, m = local / per, rem = local - m * per;
        wprep[base + m * per + frag_off(rem / 192, rem % 192, 12)] = f2b(src[local]); }
    else if (idx < 663552)   { base = 589824;  local = idx - base; src = proj_w;
        int per = 36864, m = local / per, rem = local - m * per;
        wprep[base + m * per + frag_off(rem / 192, rem % 192, 12)] = f2b(src[local]); }
    else if (idx < 688128)   { base = 663552;  local = idx - base; src = w_1x1;
        int n = local / 128, k = local - n * 128;
        wprep[base + frag_off(k, n, 12)] = f2b(src[local]); }
    else if (idx < 835584)   { base = 688128;  local = idx - base; src = w_kxk;
        int oc = local / 1152, rem = local - oc * 1152, ic = rem / 9, tap = rem - ic * 9;
        wprep[base + tap * 16384 + frag_off(ic, oc, 8)] = f2b(src[local]); }
    else if (idx < 1130496)  { base = 835584;  local = idx - base; src = w_fus;
        int oc = local / 2304, rem = local - oc * 2304, ic = rem / 9, tap = rem - ic * 9;
        wprep[base + tap * 32768 + frag_off(ic, oc, 8)] = f2b(src[local]); }
    else if (idx < 1351680)  { base = 1130496; local = idx - base; src = qkv_w;
        int per = 110592, m = local / per, rem = local - m * per;
        wprep[base + m * per + frag_off(rem / 576, rem % 576, 36)] = f2b(src[local]); }
    else                     { base = 1351680; local = idx - base; src = w_proj;
        int n = local / 192, k = local - n * 192;
        wprep[base + frag_off(k, n, 8)] = f2b(src[local]); }
}

// ---------------- NCHW fp32 -> NHWC bf16 (one (b,y) row per block) ----------------
__global__ __launch_bounds__(256) void k_tohwc(const float* __restrict__ x, bf16* __restrict__ xh)
{
    __shared__ bf16 L[64][136];
    const int br = blockIdx.x;           // b*64 + y
    const int b = br >> 6, y = br & 63;
    for (int idx = threadIdx.x; idx < 8192; idx += 256) {
        int ch = idx >> 6, xc = idx & 63;
        L[xc][ch] = f2b(x[(((size_t)b * 128 + ch) * 64 + y) * 64 + xc]);
    }
    __syncthreads();
    for (int idx = threadIdx.x; idx < 1024; idx += 256) {
        int px = idx >> 4, q = idx & 15;
        *(short8*)(void*)(xh + ((size_t)br * 64 + px) * 128 + q * 8) =
            *(const short8*)(const void*)(&L[px][q * 8]);
    }
}

// ---------------- conv1 3x3 via MFMA (implicit GEMM, NHWC bf16 in/out) + BN + SiLU ----------------
__global__ __launch_bounds__(256) void k_conv1_mfma(
    const bf16* __restrict__ xh, const bf16* __restrict__ wf,
    const float* __restrict__ gamma, const float* __restrict__ beta,
    bf16* __restrict__ h1h)
{
    __shared__ __align__(16) bf16 outL[64][136];
    const int br = blockIdx.x;
    const int b = br >> 6, y = br & 63;
    const int lane = threadIdx.x & 63, w = threadIdx.x >> 6;
    const int m0 = w * 16, kg = lane >> 4, ln16 = lane & 15;
    float4v acc[8];
    #pragma unroll
    for (int i = 0; i < 8; ++i) acc[i] = (float4v)0.f;
    #pragma unroll
    for (int tap = 0; tap < 9; ++tap) {
        const int ky = tap / 3 - 1, kx = tap % 3 - 1;
        const int yy = y + ky;
        if (yy < 0 || yy > 63) continue;
        const int px = m0 + ln16 + kx;
        const bool valid = (px >= 0) && (px < 64);
        const bf16* wt = wf + tap * 16384;
        #pragma unroll
        for (int kc = 0; kc < 4; ++kc) {
            short8 a = {0, 0, 0, 0, 0, 0, 0, 0};
            if (valid)
                a = *(const short8*)(const void*)(xh + (((size_t)(b * 64 + yy) * 64 + px) * 128) + kc * 32 + kg * 8);
            const bf16* wb = wt + (kc * 8) * 512 + lane * 8;
            #pragma unroll
            for (int nt = 0; nt < 8; ++nt) {
                short8 bfrag = *(const short8*)(const void*)(wb + nt * 512);
                acc[nt] = __builtin_amdgcn_mfma_f32_16x16x32_bf16(a, bfrag, acc[nt], 0, 0, 0);
            }
        }
    }
    #pragma unroll
    for (int nt = 0; nt < 8; ++nt) {
        int c = nt * 16 + ln16;
        float g = gamma[c], be = beta[c];
        #pragma unroll
        for (int r = 0; r < 4; ++r)
            outL[m0 + kg * 4 + r][c] = f2b(siluf(g * acc[nt][r] + be));
    }
    __syncthreads();
    for (int idx = threadIdx.x; idx < 1024; idx += 256) {
        int px = idx >> 4, q = idx & 15;
        *(short8*)(void*)(h1h + ((size_t)br * 64 + px) * 128 + q * 8) =
            *(const short8*)(const void*)(&outL[px][q * 8]);
    }
}

// ---------------- fusion conv 3x3 (K=256 from xh + ph) + BN + SiLU -> NCHW fp32 ----------------
__global__ __launch_bounds__(256) void k_convf_mfma(
    const bf16* __restrict__ xh, const bf16* __restrict__ ph,
    const bf16* __restrict__ wf,
    const float* __restrict__ gamma, const float* __restrict__ beta,
    float* __restrict__ out)
{
    __shared__ float outF[64][129];
    const int br = blockIdx.x;
    const int b = br >> 6, y = br & 63;
    const int lane = threadIdx.x & 63, w = threadIdx.x >> 6;
    const int m0 = w * 16, kg = lane >> 4, ln16 = lane & 15;
    float4v acc[8];
    #pragma unroll
    for (int i = 0; i < 8; ++i) acc[i] = (float4v)0.f;
    #pragma unroll
    for (int tap = 0; tap < 9; ++tap) {
        const int ky = tap / 3 - 1, kx = tap % 3 - 1;
        const int yy = y + ky;
        if (yy < 0 || yy > 63) continue;
        const int px = m0 + ln16 + kx;
        const bool valid = (px >= 0) && (px < 64);
        const size_t rowoff = ((size_t)(b * 64 + yy) * 64 + px) * 128;
        const bf16* wt = wf + tap * 32768;
        #pragma unroll
        for (int kc = 0; kc < 8; ++kc) {
            const bf16* src = (kc < 4) ? xh : ph;
            short8 a = {0, 0, 0, 0, 0, 0, 0, 0};
            if (valid)
                a = *(const short8*)(const void*)(src + rowoff + (kc & 3) * 32 + kg * 8);
            const bf16* wb = wt + (kc * 8) * 512 + lane * 8;
            #pragma unroll
            for (int nt = 0; nt < 8; ++nt) {
                short8 bfrag = *(const short8*)(const void*)(wb + nt * 512);
                acc[nt] = __builtin_amdgcn_mfma_f32_16x16x32_bf16(a, bfrag, acc[nt], 0, 0, 0);
            }
        }
    }
    #pragma unroll
    for (int nt = 0; nt < 8; ++nt) {
        int c = nt * 16 + ln16;
        float g = gamma[c], be = beta[c];
        #pragma unroll
        for (int r = 0; r < 4; ++r)
            outF[m0 + kg * 4 + r][c] = siluf(g * acc[nt][r] + be);
    }
    __syncthreads();
    for (int idx = threadIdx.x; idx < 8192; idx += 256) {
        int oc = idx >> 6, xcol = idx & 63;
        out[(((size_t)b * 128 + oc) * 64 + y) * 64 + xcol] = outF[xcol][oc];
    }
}

// ---------------- FUSED patchify + 1x1 + gating + MoE, M=32 row-split, 2 blocks per (b,y) ----------------
template <typename TT>
__global__ __launch_bounds__(512) void k_patchmoe(
    const bf16* __restrict__ h1h, const bf16* __restrict__ w1x1f,
    const float* __restrict__ gate_w_all, const int* __restrict__ task,
    const bf16* __restrict__ w1f, const float* __restrict__ b1,
    const bf16* __restrict__ w2f, const float* __restrict__ b2,
    TT* __restrict__ t, float* __restrict__ part)
{
    __shared__ __align__(16) bf16 outL[32][200];
    __shared__ __align__(16) bf16 hL[2][32][200];
    __shared__ __align__(16) bf16 gwL[768];
    __shared__ float dsm[32][4];
    __shared__ float sm[2][8];
    const int blk = blockIdx.x;
    const int br = blk >> 1, half = blk & 1;
    const int b = br >> 6, y = br & 63;
    const int tid = threadIdx.x;
    const int lane = tid & 63;
    const int wv = tid >> 6;             // 0..7
    const int wr = wv & 1, wc = wv >> 1; // 2 row-tiles x 4 col-groups (3 n-tiles each)
    const int kg = lane >> 4, ln16 = lane & 15;
    const int pab = (y & 7) * 8, npb = (y >> 3) * 8;
    const int m0 = wr * 16;

    for (int i = tid; i < 768; i += 512) gwL[i] = f2b(gate_w_all[(size_t)task[0] * 768 + i]);

    // ---- phase 1: patch GEMM (M=32) ----
    {
        float4v acc[3];
        #pragma unroll
        for (int i = 0; i < 3; ++i) acc[i] = (float4v)0.f;
        #pragma unroll
        for (int kc = 0; kc < 4; ++kc) {
            short8 a = *(const short8*)(const void*)(h1h + ((size_t)br * 64 + half * 32 + m0 + ln16) * 128 + kc * 32 + kg * 8);
            const bf16* wb = w1x1f + (kc * 12 + wc * 3) * 512 + lane * 8;
            #pragma unroll
            for (int nt = 0; nt < 3; ++nt) {
                short8 bfrag = *(const short8*)(const void*)(wb + nt * 512);
                acc[nt] = __builtin_amdgcn_mfma_f32_16x16x32_bf16(a, bfrag, acc[nt], 0, 0, 0);
            }
        }
        #pragma unroll
        for (int nt = 0; nt < 3; ++nt) {
            #pragma unroll
            for (int r = 0; r < 4; ++r)
                outL[m0 + kg * 4 + r][(wc * 3 + nt) * 16 + ln16] = f2b(acc[nt][r]);
        }
    }
    __syncthreads();
    // ---- phase 2: gating (32 rows, tid<128, vectorized LDS reads) ----
    if (tid < 128) {
        const int px = tid >> 2, qg = tid & 3;
        float L0 = 0.f, L1 = 0.f, L2 = 0.f, L3 = 0.f;
        #pragma unroll
        for (int j = 0; j < 6; ++j) {
            float xv[8];
            ld8(&outL[px][qg * 48 + j * 8], xv);
            #pragma unroll
            for (int k = 0; k < 8; ++k) {
                int c = qg * 48 + j * 8 + k;
                float w4[4];
                ld4(&gwL[c * 4], w4);
                L0 += xv[k] * w4[0]; L1 += xv[k] * w4[1];
                L2 += xv[k] * w4[2]; L3 += xv[k] * w4[3];
            }
        }
        L0 += __shfl_xor(L0, 1); L0 += __shfl_xor(L0, 2);
        L1 += __shfl_xor(L1, 1); L1 += __shfl_xor(L1, 2);
        L2 += __shfl_xor(L2, 1); L2 += __shfl_xor(L2, 2);
        L3 += __shfl_xor(L3, 1); L3 += __shfl_xor(L3, 2);
        float vals[8] = {0.f,0.f,0.f,0.f,0.f,0.f,0.f,0.f};
        if (qg == 0) {
            float m = fmaxf(fmaxf(L0, L1), fmaxf(L2, L3));
            float e0 = expf(L0 - m), e1 = expf(L1 - m), e2 = expf(L2 - m), e3 = expf(L3 - m);
            float s = e0 + e1 + e2 + e3;
            float p[4] = {e0 / s, e1 / s, e2 / s, e3 / s};
            int i1 = 0; float v1 = p[0];
            #pragma unroll
            for (int e = 1; e < 4; ++e) if (p[e] > v1) { v1 = p[e]; i1 = e; }
            int i2 = -1; float v2 = -1.f;
            #pragma unroll
            for (int e = 0; e < 4; ++e) if (e != i1 && p[e] > v2) { v2 = p[e]; i2 = e; }
            float gs = v1 + v2;
            float d[4] = {0.f, 0.f, 0.f, 0.f};
            d[i1] = v1 / gs; d[i2] = v2 / gs;
            dsm[px][0] = d[0]; dsm[px][1] = d[1]; dsm[px][2] = d[2]; dsm[px][3] = d[3];
            vals[0]=p[0]; vals[1]=p[1]; vals[2]=p[2]; vals[3]=p[3];
            vals[4]=d[0]>0.f?1.f:0.f; vals[5]=d[1]>0.f?1.f:0.f;
            vals[6]=d[2]>0.f?1.f:0.f; vals[7]=d[3]>0.f?1.f:0.f;
        }
        #pragma unroll
        for (int off = 32; off; off >>= 1)
            #pragma unroll
            for (int i = 0; i < 8; ++i) vals[i] += __shfl_down(vals[i], off);
        if (lane == 0)
            #pragma unroll
            for (int i = 0; i < 8; ++i) sm[wv][i] = vals[i];
    }
    __syncthreads();
    if (tid < 8)
        part[blk * 8 + tid] = sm[0][tid] + sm[1][tid];

    // ---- phase 3: MoE (A from outL, gates from dsm; dbuf hL, 1 barrier/expert) ----
    float g4[4][4];
    #pragma unroll
    for (int e = 0; e < 4; ++e)
        #pragma unroll
        for (int r = 0; r < 4; ++r)
            g4[e][r] = dsm[m0 + kg * 4 + r][e];

    float4v accT[3];
    #pragma unroll
    for (int i = 0; i < 3; ++i) accT[i] = (float4v)0.f;

    for (int e = 0; e < 4; ++e) {
        float4v acc[3];
        #pragma unroll
        for (int i = 0; i < 3; ++i) acc[i] = (float4v)0.f;
        #pragma unroll
        for (int kc = 0; kc < 6; ++kc) {
            short8 a = *(const short8*)(const void*)(&outL[m0 + ln16][kc * 32 + kg * 8]);
            const bf16* wb = w1f + (size_t)e * 36864 + (kc * 12 + wc * 3) * 512 + lane * 8;
            #pragma unroll
            for (int nt = 0; nt < 3; ++nt) {
                short8 bfrag = *(const short8*)(const void*)(wb + nt * 512);
                acc[nt] = __builtin_amdgcn_mfma_f32_16x16x32_bf16(a, bfrag, acc[nt], 0, 0, 0);
            }
        }
        bf16 (*hb)[200] = hL[e & 1];
        #pragma unroll
        for (int nt = 0; nt < 3; ++nt) {
            int c = (wc * 3 + nt) * 16 + ln16;
            float bias = b1[e * 192 + c];
            #pragma unroll
            for (int r = 0; r < 4; ++r)
                hb[m0 + kg * 4 + r][c] = f2b(geluf(acc[nt][r] + bias) * g4[e][r]);
        }
        __syncthreads();
        #pragma unroll
        for (int kc = 0; kc < 6; ++kc) {
            short8 a2 = *(const short8*)(const void*)(&hb[m0 + ln16][kc * 32 + kg * 8]);
            const bf16* wb = w2f + (size_t)e * 36864 + (kc * 12 + wc * 3) * 512 + lane * 8;
            #pragma unroll
            for (int nt = 0; nt < 3; ++nt) {
                short8 bfrag = *(const short8*)(const void*)(wb + nt * 512);
                accT[nt] = __builtin_amdgcn_mfma_f32_16x16x32_bf16(a2, bfrag, accT[nt], 0, 0, 0);
            }
        }
    }
    #pragma unroll
    for (int nt = 0; nt < 3; ++nt) {
        int c = (wc * 3 + nt) * 16 + ln16;
        #pragma unroll
        for (int r = 0; r < 4; ++r) {
            int pix = half * 32 + m0 + kg * 4 + r;
            int tokr = (b * 64 + pab + (pix & 7)) * 64 + npb + (pix >> 3);
            float v = accT[nt][r];
            #pragma unroll
            for (int e = 0; e < 4; ++e) v += g4[e][r] * b2[e * 192 + c];
            stv(&t[(size_t)tokr * 192 + c], v);
        }
    }
}

// ---------------- fused LN2 + MLP via MFMA, M=32 row-split (25.6 KB LDS -> 6 blk/CU) ----------------
// grid 4096: block handles rows [blk*32, blk*32+32). 4 waves = 2 row-tiles x 2 col-groups (6 nt).
// Per-element accumulation order identical to 64-row version (ch0:kc0..5, ch1:kc0..5) -> bit-identical.
template <typename TT>
__global__ __launch_bounds__(256) void k_mlp_mfma(
    TT* __restrict__ t, const float* __restrict__ lg, const float* __restrict__ lb,
    const bf16* __restrict__ w1f, const float* __restrict__ b1,
    const bf16* __restrict__ w2f, const float* __restrict__ b2)
{
    __shared__ __align__(16) bf16 yL[32][200];
    __shared__ __align__(16) bf16 hL[32][200];
    const int rbase = blockIdx.x * 32;
    const int tid = threadIdx.x;
    if (tid < 128) {
        const int row = tid >> 2, qg = tid & 3;
        float v[48];
        const TT* tr_ = t + (size_t)(rbase + row) * 192 + qg * 48;
        float s = 0.f, sq = 0.f;
        #pragma unroll
        for (int i = 0; i < 12; ++i) {
            float tmp[4]; ld4(tr_ + i * 4, tmp);
            #pragma unroll
            for (int j = 0; j < 4; ++j) { v[i*4+j] = tmp[j]; s += tmp[j]; sq += tmp[j]*tmp[j]; }
        }
        s  += __shfl_xor(s, 1);  s  += __shfl_xor(s, 2);
        sq += __shfl_xor(sq, 1); sq += __shfl_xor(sq, 2);
        float m = s * (1.f/192.f), var = sq * (1.f/192.f) - m*m;
        float rs = rsqrtf(var + 1e-5f);
        #pragma unroll
        for (int i = 0; i < 48; ++i) {
            int d = qg * 48 + i;
            yL[row][d] = f2b((v[i] - m) * rs * lg[d] + lb[d]);
        }
    }
    __syncthreads();
    const int lane = tid & 63, wv = tid >> 6;
    const int wr = wv & 1, wc = wv >> 1;     // 2 row-tiles x 2 col-groups
    const int m0 = wr * 16;
    const int kg = lane >> 4, ln16 = lane & 15;
    float4v accT[6];
    #pragma unroll
    for (int i = 0; i < 6; ++i) accT[i] = (float4v)0.f;
    for (int ch = 0; ch < 2; ++ch) {
        float4v acc[6];
        #pragma unroll
        for (int i = 0; i < 6; ++i) acc[i] = (float4v)0.f;
        for (int kc = 0; kc < 6; ++kc) {
            short8 a = *(const short8*)(const void*)(&yL[m0 + ln16][kc * 32 + kg * 8]);
            const bf16* wb = w1f + (size_t)(kc * 24 + ch * 12 + wc * 6) * 512 + lane * 8;
            #pragma unroll
            for (int nt = 0; nt < 6; ++nt) {
                short8 bfrag = *(const short8*)(const void*)(wb + nt * 512);
                acc[nt] = __builtin_amdgcn_mfma_f32_16x16x32_bf16(a, bfrag, acc[nt], 0, 0, 0);
            }
        }
        #pragma unroll
        for (int nt = 0; nt < 6; ++nt) {
            int c = (wc * 6 + nt) * 16 + ln16;
            float bias = b1[ch * 192 + c];
            #pragma unroll
            for (int r = 0; r < 4; ++r)
                hL[m0 + kg * 4 + r][c] = f2b(geluf(acc[nt][r] + bias));
        }
        __syncthreads();
        for (int kc = 0; kc < 6; ++kc) {
            short8 a = *(const short8*)(const void*)(&hL[m0 + ln16][kc * 32 + kg * 8]);
            const bf16* wb = w2f + (size_t)((ch * 6 + kc) * 12 + wc * 6) * 512 + lane * 8;
            #pragma unroll
            for (int nt = 0; nt < 6; ++nt) {
                short8 bfrag = *(const short8*)(const void*)(wb + nt * 512);
                accT[nt] = __builtin_amdgcn_mfma_f32_16x16x32_bf16(a, bfrag, accT[nt], 0, 0, 0);
            }
        }
        __syncthreads();
    }
    #pragma unroll
    for (int nt = 0; nt < 6; ++nt) {
        int c = (wc * 6 + nt) * 16 + ln16;
        float bias = b2[c];
        #pragma unroll
        for (int r = 0; r < 4; ++r) {
            TT* p = &t[(size_t)(rbase + m0 + kg * 4 + r) * 192 + c];
            stv(p, ldv(p) + accT[nt][r] + bias);
        }
    }
}

// ---------------- fused LN1 + QKV + attention + PROJ, compact-LDS, ILP-paired QKV ----------------
template <typename TT>
__global__ __launch_bounds__(256) void k_attn_mfma(
    TT* __restrict__ t, const float* __restrict__ lg, const float* __restrict__ lb,
    const bf16* __restrict__ qkvwf, const float* __restrict__ qkvb,
    const bf16* __restrict__ pwf, const float* __restrict__ pb)
{
    __shared__ __align__(16) bf16 smem[39424];
    bf16* Qs = smem;              // [64][200], cols h*48+d
    bf16* Ks = smem + 12800;      // [64][200]
    bf16* vT = smem + 25600;      // [4][48][72]
    bf16* pL = smem;              // overlay
    bf16* y2L = smem + 25600;     // overlay, [64][200]
    const int n = blockIdx.x;
    const int tid = threadIdx.x;
    const int w = tid >> 6, lane = tid & 63;
    const int kg = lane >> 4, ln16 = lane & 15;
    const int row = w * 16 + ln16;
    const short8 zfrag = {0, 0, 0, 0, 0, 0, 0, 0};

    // LN in registers, producing A-fragments directly
    short8 afr[6];
    {
        float v[48];
        float s = 0.f, sq = 0.f;
        const TT* tp = t + (size_t)n * 12288 + row * 192 + kg * 8;
        #pragma unroll
        for (int c = 0; c < 6; ++c) {
            float tmp[8]; ld8(tp + c * 32, tmp);
            #pragma unroll
            for (int j = 0; j < 8; ++j) { v[c*8+j] = tmp[j]; s += tmp[j]; sq += tmp[j]*tmp[j]; }
        }
        s  += __shfl_xor(s, 16);  s  += __shfl_xor(s, 32);
        sq += __shfl_xor(sq, 16); sq += __shfl_xor(sq, 32);
        float m = s * (1.f/192.f), var = sq * (1.f/192.f) - m * m;
        float rs = rsqrtf(var + 1e-5f);
        #pragma unroll
        for (int c = 0; c < 6; ++c) {
            float g8[8], b8[8];
            ld8(lg + kg * 8 + c * 32, g8);
            ld8(lb + kg * 8 + c * 32, b8);
            bf16 pk[8];
            #pragma unroll
            for (int j = 0; j < 8; ++j)
                pk[j] = f2b((v[c*8+j] - m) * rs * g8[j] + b8[j]);
            afr[c] = *(const short8*)(const void*)pk;
        }
    }

    const float qscale = 0.14433756729740644f;  // 1/sqrt(48)
    // epilogue scatter for one nt column group
    auto qkv_store = [&](int nt, float4v acc) {
        const int which = nt / 12, h = (nt % 12) / 3, dt = nt % 3;
        const int d = dt * 16 + ln16;
        const float bias = qkvb[nt * 16 + ln16];
        if (which == 0) {
            #pragma unroll
            for (int r = 0; r < 4; ++r)
                Qs[(w * 16 + kg * 4 + r) * 200 + h * 48 + d] = f2b((acc[r] + bias) * qscale);
        } else if (which == 1) {
            #pragma unroll
            for (int r = 0; r < 4; ++r)
                Ks[(w * 16 + kg * 4 + r) * 200 + h * 48 + d] = f2b(acc[r] + bias);
        } else {
            #pragma unroll
            for (int r = 0; r < 4; ++r)
                vT[h * 3456 + d * 72 + (w * 16 + kg * 4 + r)] = f2b(acc[r] + bias);
        }
    };
    // QKV GEMM with paired nt for 2x MFMA ILP (per-chain order unchanged)
    for (int nt2 = 0; nt2 < 18; ++nt2) {
        const int ntA = nt2 * 2, ntB = ntA + 1;
        float4v accA = (float4v)0.f, accB = (float4v)0.f;
        const bf16* wbA = qkvwf + ntA * 512 + lane * 8;
        const bf16* wbB = qkvwf + ntB * 512 + lane * 8;
        #pragma unroll
        for (int kc = 0; kc < 6; ++kc) {
            short8 bfA = *(const short8*)(const void*)(wbA + kc * 36 * 512);
            short8 bfB = *(const short8*)(const void*)(wbB + kc * 36 * 512);
            accA = __builtin_amdgcn_mfma_f32_16x16x32_bf16(afr[kc], bfA, accA, 0, 0, 0);
            accB = __builtin_amdgcn_mfma_f32_16x16x32_bf16(afr[kc], bfB, accB, 0, 0, 0);
        }
        qkv_store(ntA, accA);
        qkv_store(ntB, accB);
    }
    __syncthreads();

    // QK^T for head w: K-dim 48 = kc0 full + kc1 half (kg>=2 slices zero)
    float4v sacc[4][4];
    #pragma unroll
    for (int mt = 0; mt < 4; ++mt)
        #pragma unroll
        for (int nt = 0; nt < 4; ++nt) sacc[mt][nt] = (float4v)0.f;
    #pragma unroll
    for (int kc = 0; kc < 2; ++kc) {
        const bool kv = (kc == 0) || (kg < 2);
        short8 aq[4], bk[4];
        #pragma unroll
        for (int mt = 0; mt < 4; ++mt)
            aq[mt] = kv ? *(const short8*)(const void*)(Qs + (mt * 16 + ln16) * 200 + w * 48 + kc * 32 + kg * 8) : zfrag;
        #pragma unroll
        for (int nt = 0; nt < 4; ++nt)
            bk[nt] = kv ? *(const short8*)(const void*)(Ks + (nt * 16 + ln16) * 200 + w * 48 + kc * 32 + kg * 8) : zfrag;
        #pragma unroll
        for (int mt = 0; mt < 4; ++mt)
            #pragma unroll
            for (int nt = 0; nt < 4; ++nt)
                sacc[mt][nt] = __builtin_amdgcn_mfma_f32_16x16x32_bf16(aq[mt], bk[nt], sacc[mt][nt], 0, 0, 0);
    }
    __syncthreads();   // all Q/K reads done before pL overlay writes

    #pragma unroll
    for (int mt = 0; mt < 4; ++mt) {
        #pragma unroll
        for (int r = 0; r < 4; ++r) {
            float mx = sacc[mt][0][r];
            #pragma unroll
            for (int nt = 1; nt < 4; ++nt) mx = fmaxf(mx, sacc[mt][nt][r]);
            mx = fmaxf(mx, __shfl_xor(mx, 1)); mx = fmaxf(mx, __shfl_xor(mx, 2));
            mx = fmaxf(mx, __shfl_xor(mx, 4)); mx = fmaxf(mx, __shfl_xor(mx, 8));
            float e[4], sum = 0.f;
            #pragma unroll
            for (int nt = 0; nt < 4; ++nt) { e[nt] = expf(sacc[mt][nt][r] - mx); sum += e[nt]; }
            sum += __shfl_xor(sum, 1); sum += __shfl_xor(sum, 2);
            sum += __shfl_xor(sum, 4); sum += __shfl_xor(sum, 8);
            float inv = 1.f / sum;
            #pragma unroll
            for (int nt = 0; nt < 4; ++nt)
                pL[w * 4608 + (mt * 16 + kg * 4 + r) * 72 + nt * 16 + ln16] = f2b(e[nt] * inv);
        }
    }
    float4v oacc[4][3];
    #pragma unroll
    for (int mt = 0; mt < 4; ++mt)
        #pragma unroll
        for (int nt = 0; nt < 3; ++nt) oacc[mt][nt] = (float4v)0.f;
    #pragma unroll
    for (int kc = 0; kc < 2; ++kc) {
        short8 ap[4], bv[3];
        #pragma unroll
        for (int mt = 0; mt < 4; ++mt)
            ap[mt] = *(const short8*)(const void*)(pL + w * 4608 + (mt * 16 + ln16) * 72 + kc * 32 + kg * 8);
        #pragma unroll
        for (int nt = 0; nt < 3; ++nt)
            bv[nt] = *(const short8*)(const void*)(vT + w * 3456 + (nt * 16 + ln16) * 72 + kc * 32 + kg * 8);
        #pragma unroll
        for (int mt = 0; mt < 4; ++mt)
            #pragma unroll
            for (int nt = 0; nt < 3; ++nt)
                oacc[mt][nt] = __builtin_amdgcn_mfma_f32_16x16x32_bf16(ap[mt], bv[nt], oacc[mt][nt], 0, 0, 0);
    }
    // ---- stage y2 in LDS (overlay on vT; all PV reads done) ----
    __syncthreads();
    #pragma unroll
    for (int mt = 0; mt < 4; ++mt)
        #pragma unroll
        for (int nt = 0; nt < 3; ++nt)
            #pragma unroll
            for (int r = 0; r < 4; ++r)
                y2L[(mt * 16 + kg * 4 + r) * 200 + w * 48 + nt * 16 + ln16] = f2b(oacc[mt][nt][r]);
    __syncthreads();
    // ---- proj GEMM: t += y2 @ proj_w + pb ----
    float4v pacc[12];
    #pragma unroll
    for (int i = 0; i < 12; ++i) pacc[i] = (float4v)0.f;
    #pragma unroll
    for (int kc = 0; kc < 6; ++kc) {
        short8 a = *(const short8*)(const void*)(y2L + row * 200 + kc * 32 + kg * 8);
        const bf16* wb = pwf + (kc * 12) * 512 + lane * 8;
        #pragma unroll
        for (int nt = 0; nt < 12; ++nt) {
            short8 bfrag = *(const short8*)(const void*)(wb + nt * 512);
            pacc[nt] = __builtin_amdgcn_mfma_f32_16x16x32_bf16(a, bfrag, pacc[nt], 0, 0, 0);
        }
    }
    #pragma unroll
    for (int nt = 0; nt < 12; ++nt) {
        int c = nt * 16 + ln16;
        float bias = pb[c];
        #pragma unroll
        for (int r = 0; r < 4; ++r) {
            TT* p = &t[((size_t)n * 64 + w * 16 + kg * 4 + r) * 192 + c];
            stv(p, ldv(p) + pacc[nt][r] + bias);
        }
    }
}

// ---------------- fused final LN + unpatchify + 1x1 (192->128) + BN + SiLU via MFMA ----------------
template <typename TT>
__global__ __launch_bounds__(256) void k_unpatch_mfma(
    const TT* __restrict__ t, const float* __restrict__ ng, const float* __restrict__ nb,
    const bf16* __restrict__ wpf, const float* __restrict__ gamma, const float* __restrict__ beta,
    bf16* __restrict__ ph)
{
    __shared__ __align__(16) bf16 outL[64][136];
    const int blk = blockIdx.x;          // = b*64 + pa
    const int b = blk >> 6, pa = blk & 63;
    const int tid = threadIdx.x;
    const int w = tid >> 6, lane = tid & 63;
    const int kg = lane >> 4, ln16 = lane & 15;
    const int row = w * 16 + ln16;       // np index

    short8 afr[6];
    {
        float v[48];
        float s = 0.f, sq = 0.f;
        const TT* tp = t + ((size_t)blk * 64 + row) * 192 + kg * 8;
        #pragma unroll
        for (int c = 0; c < 6; ++c) {
            float tmp[8]; ld8(tp + c * 32, tmp);
            #pragma unroll
            for (int j = 0; j < 8; ++j) { v[c*8+j] = tmp[j]; s += tmp[j]; sq += tmp[j]*tmp[j]; }
        }
        s  += __shfl_xor(s, 16);  s  += __shfl_xor(s, 32);
        sq += __shfl_xor(sq, 16); sq += __shfl_xor(sq, 32);
        float m = s * (1.f/192.f), var = sq * (1.f/192.f) - m * m;
        float rs = rsqrtf(var + 1e-5f);
        #pragma unroll
        for (int c = 0; c < 6; ++c) {
            float g8[8], b8[8];
            ld8(ng + kg * 8 + c * 32, g8);
            ld8(nb + kg * 8 + c * 32, b8);
            bf16 pk[8];
            #pragma unroll
            for (int j = 0; j < 8; ++j)
                pk[j] = f2b((v[c*8+j] - m) * rs * g8[j] + b8[j]);
            afr[c] = *(const short8*)(const void*)pk;
        }
    }

    float4v acc[8];
    #pragma unroll
    for (int i = 0; i < 8; ++i) acc[i] = (float4v)0.f;
    #pragma unroll
    for (int kc = 0; kc < 6; ++kc) {
        const bf16* wb = wpf + (kc * 8) * 512 + lane * 8;
        #pragma unroll
        for (int nt = 0; nt < 8; ++nt) {
            short8 bfrag = *(const short8*)(const void*)(wb + nt * 512);
            acc[nt] = __builtin_amdgcn_mfma_f32_16x16x32_bf16(afr[kc], bfrag, acc[nt], 0, 0, 0);
        }
    }
    #pragma unroll
    for (int nt = 0; nt < 8; ++nt) {
        int c = nt * 16 + ln16;
        float g = gamma[c], be = beta[c];
        #pragma unroll
        for (int r = 0; r < 4; ++r)
            outL[w * 16 + kg * 4 + r][c] = f2b(siluf(g * acc[nt][r] + be));
    }
    __syncthreads();
    for (int idx = tid; idx < 1024; idx += 256) {
        int np = idx >> 4, q = idx & 15;
        int yy = (np >> 3) * 8 + (pa >> 3), xx = (np & 7) * 8 + (pa & 7);
        *(short8*)(void*)(ph + ((size_t)(b * 64 + yy) * 64 + xx) * 128 + q * 8) =
            *(const short8*)(const void*)(&outL[np][q * 8]);
    }
}

// ---------------- moe loss: parallel deterministic reduction over 4096x8 partials ----------------
__global__ __launch_bounds__(256) void k_loss(const float* __restrict__ part, float* __restrict__ out)
{
    __shared__ float red[8][33];
    const int tid = threadIdx.x;
    const int e = tid & 7, g = tid >> 3;   // 32 groups per e
    float s = 0.f;
    for (int i = g; i < 4096; i += 32) s += part[i * 8 + e];
    red[e][g] = s;
    __syncthreads();
    if (tid < 8) {
        float t2 = 0.f;
        for (int g2 = 0; g2 < 32; ++g2) t2 += red[tid][g2];
        red[tid][32] = t2;
    }
    __syncthreads();
    if (tid == 0) {
        float L = 0.f;
        for (int e2 = 0; e2 < 4; ++e2)
            L += (red[e2][32] / 131072.f) * (red[4 + e2][32] / 131072.f);
        out[16777216] = 4.f * L;
    }
}

template <typename TT>
static void run_pipeline(const float* x, const float* w_kxk, const float* bn1_g, const float* bn1_b,
                         const float* w_1x1, const float* gate_w,
                         const float* moe_w1, const float* moe_b1, const float* moe_w2, const float* moe_b2,
                         const float* ln1_g, const float* ln1_b, const float* qkv_w, const float* qkv_b,
                         const float* proj_w, const float* proj_b, const float* ln2_g, const float* ln2_b,
                         const float* fc1_w, const float* fc1_b, const float* fc2_w, const float* fc2_b,
                         const float* nrm_g, const float* nrm_b, const float* w_proj, const float* bn2_g,
                         const float* bn2_b, const float* w_fus, const float* bn3_g, const float* bn3_b,
                         const int* task, float* out, bf16* xh, bf16* tok, TT* t, float* part,
                         bf16* wprep, hipStream_t stream)
{
    // fragment regions inside wprep (prefix == k_prep_all job table)
    bf16* moeW1f = wprep;                 // 147456
    bf16* moeW2f = wprep + 147456;        // 147456
    bf16* fc1f   = wprep + 294912;        // 147456
    bf16* fc2f   = wprep + 442368;        // 147456
    bf16* projWf = wprep + 589824;        // 73728
    bf16* w1x1f  = wprep + 663552;        // 24576
    bf16* convW1f= wprep + 688128;        // 147456
    bf16* convWFf= wprep + 835584;        // 294912
    bf16* qkvWf  = wprep + 1130496;       // 221184
    bf16* wpjf   = wprep + 1351680;       // 24576 -> total 1376256 elems
    hipLaunchKernelGGL(k_prep_all, dim3(5376), dim3(256), 0, stream,
                       moe_w1, moe_w2, fc1_w, fc2_w, proj_w, w_1x1, w_kxk, w_fus, qkv_w, w_proj,
                       wprep);

    bf16* h1h = (bf16*)out;  // d_out used as NHWC bf16 scratch; fully rewritten by final conv
    hipLaunchKernelGGL(k_tohwc, dim3(2048), dim3(256), 0, stream, x, xh);
    hipLaunchKernelGGL(k_conv1_mfma, dim3(2048), dim3(256), 0, stream, xh, convW1f, bn1_g, bn1_b, h1h);
    hipLaunchKernelGGL(k_patchmoe<TT>, dim3(4096), dim3(512), 0, stream,
                       h1h, w1x1f, gate_w, task, moeW1f, moe_b1, moeW2f, moe_b2, t, part);
    for (int l = 0; l < 2; ++l) {
        hipLaunchKernelGGL(k_attn_mfma<TT>, dim3(2048), dim3(256), 0, stream,
                           t, ln1_g + l * 192, ln1_b + l * 192,
                           qkvWf + (size_t)l * 110592, qkv_b + l * 576,
                           projWf + (size_t)l * 36864, proj_b + l * 192);
        hipLaunchKernelGGL(k_mlp_mfma<TT>, dim3(4096), dim3(256), 0, stream,
                           t, ln2_g + l * 192, ln2_b + l * 192,
                           fc1f + (size_t)l * 73728, fc1_b + l * 384,
                           fc2f + (size_t)l * 73728, fc2_b + l * 192);
    }
    bf16* ph = tok;  // tok region used as NHWC p
    hipLaunchKernelGGL(k_unpatch_mfma<TT>, dim3(2048), dim3(256), 0, stream,
                       t, nrm_g, nrm_b, wpjf, bn2_g, bn2_b, ph);
    hipLaunchKernelGGL(k_convf_mfma, dim3(2048), dim3(256), 0, stream,
                       xh, ph, convWFf, bn3_g, bn3_b, out);
    hipLaunchKernelGGL(k_loss, dim3(1), dim3(256), 0, stream, part, out);
}

extern "C" void kernel_launch(void* const* d_in, const int* in_sizes, int n_in,
                              void* d_out, int out_size, void* d_ws, size_t ws_size,
                              hipStream_t stream) {
    const float* x      = (const float*)d_in[0];
    const float* w_kxk  = (const float*)d_in[1];
    const float* bn1_g  = (const float*)d_in[2];
    const float* bn1_b  = (const float*)d_in[3];
    const float* w_1x1  = (const float*)d_in[4];
    const float* gate_w = (const float*)d_in[5];
    const float* moe_w1 = (const float*)d_in[6];
    const float* moe_b1 = (const float*)d_in[7];
    const float* moe_w2 = (const float*)d_in[8];
    const float* moe_b2 = (const float*)d_in[9];
    const float* ln1_g  = (const float*)d_in[10];
    const float* ln1_b  = (const float*)d_in[11];
    const float* qkv_w  = (const float*)d_in[12];
    const float* qkv_b  = (const float*)d_in[13];
    const float* proj_w = (const float*)d_in[14];
    const float* proj_b = (const float*)d_in[15];
    const float* ln2_g  = (const float*)d_in[16];
    const float* ln2_b  = (const float*)d_in[17];
    const float* fc1_w  = (const float*)d_in[18];
    const float* fc1_b  = (const float*)d_in[19];
    const float* fc2_w  = (const float*)d_in[20];
    const float* fc2_b  = (const float*)d_in[21];
    const float* nrm_g  = (const float*)d_in[22];
    const float* nrm_b  = (const float*)d_in[23];
    const float* w_proj = (const float*)d_in[24];
    const float* bn2_g  = (const float*)d_in[25];
    const float* bn2_b  = (const float*)d_in[26];
    const float* w_fus  = (const float*)d_in[27];
    const float* bn3_g  = (const float*)d_in[28];
    const float* bn3_b  = (const float*)d_in[29];
    const int*  task    = (const int*)d_in[30];

    char* wsb = (char*)d_ws;
    const size_t XHB   = 33554432ull;    // NHWC bf16 x
    const size_t TOKB  = 50331648ull;    // ph region
    const size_t T16B  = 50331648ull;    // bf16 residual stream
    const size_t DENB  = 2097152ull;     // part (4096*8 fp32 = 128 KB) lives here
    bf16*  t     = (bf16*)(wsb + XHB + TOKB);
    float* part  = (float*)(wsb + XHB + TOKB + T16B);
    bf16*  wprep = (bf16*)(wsb + XHB + TOKB + T16B + DENB);
    bf16* xh  = (bf16*)wsb;
    bf16* tok = (bf16*)(wsb + XHB);
    float* out = (float*)d_out;

    run_pipeline<bf16>(x, w_kxk, bn1_g, bn1_b, w_1x1, gate_w, moe_w1, moe_b1, moe_w2, moe_b2,
                       ln1_g, ln1_b, qkv_w, qkv_b, proj_w, proj_b, ln2_g, ln2_b,
                       fc1_w, fc1_b, fc2_w, fc2_b, nrm_g, nrm_b, w_proj, bn2_g, bn2_b,
                       w_fus, bn3_g, bn3_b, task, out, xh, tok, t, part, wprep, stream);
}

// Round 25
// 1043.825 us; speedup vs baseline: 1.0924x; 1.0924x over previous
//
#include <hip/hip_runtime.h>
#include <hip/hip_bf16.h>
#include <cmath>

typedef __hip_bfloat16 bf16;
typedef __attribute__((ext_vector_type(8))) short short8;
typedef __attribute__((ext_vector_type(4))) float float4v;

__device__ __forceinline__ float b2f(bf16 v) { return __bfloat162float(v); }
__device__ __forceinline__ bf16  f2b(float v) { return __float2bfloat16(v); }
__device__ __forceinline__ float bfr(unsigned int u) { union { float f; unsigned int i; } c; c.i = u << 16; return c.f; }
__device__ __forceinline__ void ld4(const float* p, float* o) {
    float4 q = *(const float4*)p; o[0]=q.x; o[1]=q.y; o[2]=q.z; o[3]=q.w;
}
__device__ __forceinline__ void ld4(const bf16* p, float* o) {
    const uint2 q = *(const uint2*)p;
    o[0] = bfr(q.x & 0xffffu); o[1] = bfr(q.x >> 16);
    o[2] = bfr(q.y & 0xffffu); o[3] = bfr(q.y >> 16);
}
template <typename T>
__device__ __forceinline__ void ld8(const T* p, float* o) { ld4(p, o); ld4(p + 4, o + 4); }
__device__ __forceinline__ float ldv(const float* p) { return *p; }
__device__ __forceinline__ float ldv(const bf16* p)  { return b2f(*p); }
__device__ __forceinline__ void  stv(float* p, float v) { *p = v; }
__device__ __forceinline__ void  stv(bf16* p, float v)  { *p = f2b(v); }

__device__ __forceinline__ float siluf(float x) { return x / (1.f + expf(-x)); }
__device__ __forceinline__ float geluf(float x) { return 0.5f * x * (1.f + erff(x * 0.70710678118654752f)); }

// ---------------- fragment-offset helper ----------------
__device__ __forceinline__ int frag_off(int k, int n, int NT) {
    return ((k >> 5) * NT + (n >> 4)) * 512 + (((k >> 3) & 3) * 16 + (n & 15)) * 8 + (k & 7);
}

// ---------------- ONE merged weight-prep kernel (all 10 jobs) ----------------
__global__ __launch_bounds__(256) void k_prep_all(
    const float* __restrict__ moe_w1, const float* __restrict__ moe_w2,
    const float* __restrict__ fc1_w, const float* __restrict__ fc2_w,
    const float* __restrict__ proj_w, const float* __restrict__ w_1x1,
    const float* __restrict__ w_kxk, const float* __restrict__ w_fus,
    const float* __restrict__ qkv_w, const float* __restrict__ w_proj,
    bf16* __restrict__ wprep)
{
    const int idx = blockIdx.x * 256 + threadIdx.x;
    if (idx >= 1376256) return;
    int base, local;
    const float* src;
    if (idx < 147456)        { base = 0;       local = idx - base; src = moe_w1;
        int per = 36864, m = local / per, rem = local - m * per;
        wprep[base + m * per + frag_off(rem / 192, rem % 192, 12)] = f2b(src[local]); }
    else if (idx < 294912)   { base = 147456;  local = idx - base; src = moe_w2;
        int per = 36864, m = local / per, rem = local - m * per;
        wprep[base + m * per + frag_off(rem / 192, rem % 192, 12)] = f2b(src[local]); }
    else if (idx < 442368)   { base = 294912;  local = idx - base; src = fc1_w;
        int per = 73728, m = local / per, rem = local - m * per;
        wprep[base + m * per + frag_off(rem / 384, rem % 384, 24)] = f2b(src[local]); }
    else if (idx < 589824)   { base = 442368;  local = idx - base; src = fc2_w;
        int per = 73728, m = local / per, rem = local - m * per;
        wprep[base + m * per + frag_off(rem / 192, rem % 192, 12)] = f2b(src[local]); }
    else if (idx < 663552)   { base = 589824;  local = idx - base; src = proj_w;
        int per = 36864, m = local / per, rem = local - m * per;
        wprep[base + m * per + frag_off(rem / 192, rem % 192, 12)] = f2b(src[local]); }
    else if (idx < 688128)   { base = 663552;  local = idx - base; src = w_1x1;
        int n = local / 128, k = local - n * 128;
        wprep[base + frag_off(k, n, 12)] = f2b(src[local]); }
    else if (idx < 835584)   { base = 688128;  local = idx - base; src = w_kxk;
        int oc = local / 1152, rem = local - oc * 1152, ic = rem / 9, tap = rem - ic * 9;
        wprep[base + tap * 16384 + frag_off(ic, oc, 8)] = f2b(src[local]); }
    else if (idx < 1130496)  { base = 835584;  local = idx - base; src = w_fus;
        int oc = local / 2304, rem = local - oc * 2304, ic = rem / 9, tap = rem - ic * 9;
        wprep[base + tap * 32768 + frag_off(ic, oc, 8)] = f2b(src[local]); }
    else if (idx < 1351680)  { base = 1130496; local = idx - base; src = qkv_w;
        int per = 110592, m = local / per, rem = local - m * per;
        wprep[base + m * per + frag_off(rem / 576, rem % 576, 36)] = f2b(src[local]); }
    else                     { base = 1351680; local = idx - base; src = w_proj;
        int n = local / 192, k = local - n * 192;
        wprep[base + frag_off(k, n, 8)] = f2b(src[local]); }
}

// ---------------- NCHW fp32 -> NHWC bf16 (one (b,y) row per block) ----------------
__global__ __launch_bounds__(256) void k_tohwc(const float* __restrict__ x, bf16* __restrict__ xh)
{
    __shared__ bf16 L[64][136];
    const int br = blockIdx.x;           // b*64 + y
    const int b = br >> 6, y = br & 63;
    for (int idx = threadIdx.x; idx < 8192; idx += 256) {
        int ch = idx >> 6, xc = idx & 63;
        L[xc][ch] = f2b(x[(((size_t)b * 128 + ch) * 64 + y) * 64 + xc]);
    }
    __syncthreads();
    for (int idx = threadIdx.x; idx < 1024; idx += 256) {
        int px = idx >> 4, q = idx & 15;
        *(short8*)(void*)(xh + ((size_t)br * 64 + px) * 128 + q * 8) =
            *(const short8*)(const void*)(&L[px][q * 8]);
    }
}

// ---------------- conv1 3x3 via MFMA (implicit GEMM, NHWC bf16 in/out) + BN + SiLU ----------------
__global__ __launch_bounds__(256) void k_conv1_mfma(
    const bf16* __restrict__ xh, const bf16* __restrict__ wf,
    const float* __restrict__ gamma, const float* __restrict__ beta,
    bf16* __restrict__ h1h)
{
    __shared__ __align__(16) bf16 outL[64][136];
    const int br = blockIdx.x;
    const int b = br >> 6, y = br & 63;
    const int lane = threadIdx.x & 63, w = threadIdx.x >> 6;
    const int m0 = w * 16, kg = lane >> 4, ln16 = lane & 15;
    float4v acc[8];
    #pragma unroll
    for (int i = 0; i < 8; ++i) acc[i] = (float4v)0.f;
    #pragma unroll
    for (int tap = 0; tap < 9; ++tap) {
        const int ky = tap / 3 - 1, kx = tap % 3 - 1;
        const int yy = y + ky;
        if (yy < 0 || yy > 63) continue;
        const int px = m0 + ln16 + kx;
        const bool valid = (px >= 0) && (px < 64);
        const bf16* wt = wf + tap * 16384;
        #pragma unroll
        for (int kc = 0; kc < 4; ++kc) {
            short8 a = {0, 0, 0, 0, 0, 0, 0, 0};
            if (valid)
                a = *(const short8*)(const void*)(xh + (((size_t)(b * 64 + yy) * 64 + px) * 128) + kc * 32 + kg * 8);
            const bf16* wb = wt + (kc * 8) * 512 + lane * 8;
            #pragma unroll
            for (int nt = 0; nt < 8; ++nt) {
                short8 bfrag = *(const short8*)(const void*)(wb + nt * 512);
                acc[nt] = __builtin_amdgcn_mfma_f32_16x16x32_bf16(a, bfrag, acc[nt], 0, 0, 0);
            }
        }
    }
    #pragma unroll
    for (int nt = 0; nt < 8; ++nt) {
        int c = nt * 16 + ln16;
        float g = gamma[c], be = beta[c];
        #pragma unroll
        for (int r = 0; r < 4; ++r)
            outL[m0 + kg * 4 + r][c] = f2b(siluf(g * acc[nt][r] + be));
    }
    __syncthreads();
    for (int idx = threadIdx.x; idx < 1024; idx += 256) {
        int px = idx >> 4, q = idx & 15;
        *(short8*)(void*)(h1h + ((size_t)br * 64 + px) * 128 + q * 8) =
            *(const short8*)(const void*)(&outL[px][q * 8]);
    }
}

// ---------------- fusion conv 3x3 (K=256 from xh + ph) + BN + SiLU -> NCHW fp32 ----------------
__global__ __launch_bounds__(256) void k_convf_mfma(
    const bf16* __restrict__ xh, const bf16* __restrict__ ph,
    const bf16* __restrict__ wf,
    const float* __restrict__ gamma, const float* __restrict__ beta,
    float* __restrict__ out)
{
    __shared__ float outF[64][129];
    const int br = blockIdx.x;
    const int b = br >> 6, y = br & 63;
    const int lane = threadIdx.x & 63, w = threadIdx.x >> 6;
    const int m0 = w * 16, kg = lane >> 4, ln16 = lane & 15;
    float4v acc[8];
    #pragma unroll
    for (int i = 0; i < 8; ++i) acc[i] = (float4v)0.f;
    #pragma unroll
    for (int tap = 0; tap < 9; ++tap) {
        const int ky = tap / 3 - 1, kx = tap % 3 - 1;
        const int yy = y + ky;
        if (yy < 0 || yy > 63) continue;
        const int px = m0 + ln16 + kx;
        const bool valid = (px >= 0) && (px < 64);
        const size_t rowoff = ((size_t)(b * 64 + yy) * 64 + px) * 128;
        const bf16* wt = wf + tap * 32768;
        #pragma unroll
        for (int kc = 0; kc < 8; ++kc) {
            const bf16* src = (kc < 4) ? xh : ph;
            short8 a = {0, 0, 0, 0, 0, 0, 0, 0};
            if (valid)
                a = *(const short8*)(const void*)(src + rowoff + (kc & 3) * 32 + kg * 8);
            const bf16* wb = wt + (kc * 8) * 512 + lane * 8;
            #pragma unroll
            for (int nt = 0; nt < 8; ++nt) {
                short8 bfrag = *(const short8*)(const void*)(wb + nt * 512);
                acc[nt] = __builtin_amdgcn_mfma_f32_16x16x32_bf16(a, bfrag, acc[nt], 0, 0, 0);
            }
        }
    }
    #pragma unroll
    for (int nt = 0; nt < 8; ++nt) {
        int c = nt * 16 + ln16;
        float g = gamma[c], be = beta[c];
        #pragma unroll
        for (int r = 0; r < 4; ++r)
            outF[m0 + kg * 4 + r][c] = siluf(g * acc[nt][r] + be);
    }
    __syncthreads();
    for (int idx = threadIdx.x; idx < 8192; idx += 256) {
        int oc = idx >> 6, xcol = idx & 63;
        out[(((size_t)b * 128 + oc) * 64 + y) * 64 + xcol] = outF[xcol][oc];
    }
}

// ---------------- FUSED patchify + 1x1 + gating + MoE, M=32 row-split, 2 blocks per (b,y) ----------------
template <typename TT>
__global__ __launch_bounds__(512) void k_patchmoe(
    const bf16* __restrict__ h1h, const bf16* __restrict__ w1x1f,
    const float* __restrict__ gate_w_all, const int* __restrict__ task,
    const bf16* __restrict__ w1f, const float* __restrict__ b1,
    const bf16* __restrict__ w2f, const float* __restrict__ b2,
    TT* __restrict__ t, float* __restrict__ part)
{
    __shared__ __align__(16) bf16 outL[32][200];
    __shared__ __align__(16) bf16 hL[2][32][200];
    __shared__ __align__(16) bf16 gwL[768];
    __shared__ float dsm[32][4];
    __shared__ float sm[2][8];
    const int blk = blockIdx.x;
    const int br = blk >> 1, half = blk & 1;
    const int b = br >> 6, y = br & 63;
    const int tid = threadIdx.x;
    const int lane = tid & 63;
    const int wv = tid >> 6;             // 0..7
    const int wr = wv & 1, wc = wv >> 1; // 2 row-tiles x 4 col-groups (3 n-tiles each)
    const int kg = lane >> 4, ln16 = lane & 15;
    const int pab = (y & 7) * 8, npb = (y >> 3) * 8;
    const int m0 = wr * 16;

    for (int i = tid; i < 768; i += 512) gwL[i] = f2b(gate_w_all[(size_t)task[0] * 768 + i]);

    // ---- phase 1: patch GEMM (M=32) ----
    {
        float4v acc[3];
        #pragma unroll
        for (int i = 0; i < 3; ++i) acc[i] = (float4v)0.f;
        #pragma unroll
        for (int kc = 0; kc < 4; ++kc) {
            short8 a = *(const short8*)(const void*)(h1h + ((size_t)br * 64 + half * 32 + m0 + ln16) * 128 + kc * 32 + kg * 8);
            const bf16* wb = w1x1f + (kc * 12 + wc * 3) * 512 + lane * 8;
            #pragma unroll
            for (int nt = 0; nt < 3; ++nt) {
                short8 bfrag = *(const short8*)(const void*)(wb + nt * 512);
                acc[nt] = __builtin_amdgcn_mfma_f32_16x16x32_bf16(a, bfrag, acc[nt], 0, 0, 0);
            }
        }
        #pragma unroll
        for (int nt = 0; nt < 3; ++nt) {
            #pragma unroll
            for (int r = 0; r < 4; ++r)
                outL[m0 + kg * 4 + r][(wc * 3 + nt) * 16 + ln16] = f2b(acc[nt][r]);
        }
    }
    __syncthreads();
    // ---- phase 2: gating (32 rows, tid<128, vectorized LDS reads) ----
    if (tid < 128) {
        const int px = tid >> 2, qg = tid & 3;
        float L0 = 0.f, L1 = 0.f, L2 = 0.f, L3 = 0.f;
        #pragma unroll
        for (int j = 0; j < 6; ++j) {
            float xv[8];
            ld8(&outL[px][qg * 48 + j * 8], xv);
            #pragma unroll
            for (int k = 0; k < 8; ++k) {
                int c = qg * 48 + j * 8 + k;
                float w4[4];
                ld4(&gwL[c * 4], w4);
                L0 += xv[k] * w4[0]; L1 += xv[k] * w4[1];
                L2 += xv[k] * w4[2]; L3 += xv[k] * w4[3];
            }
        }
        L0 += __shfl_xor(L0, 1); L0 += __shfl_xor(L0, 2);
        L1 += __shfl_xor(L1, 1); L1 += __shfl_xor(L1, 2);
        L2 += __shfl_xor(L2, 1); L2 += __shfl_xor(L2, 2);
        L3 += __shfl_xor(L3, 1); L3 += __shfl_xor(L3, 2);
        float vals[8] = {0.f,0.f,0.f,0.f,0.f,0.f,0.f,0.f};
        if (qg == 0) {
            float m = fmaxf(fmaxf(L0, L1), fmaxf(L2, L3));
            float e0 = expf(L0 - m), e1 = expf(L1 - m), e2 = expf(L2 - m), e3 = expf(L3 - m);
            float s = e0 + e1 + e2 + e3;
            float p[4] = {e0 / s, e1 / s, e2 / s, e3 / s};
            int i1 = 0; float v1 = p[0];
            #pragma unroll
            for (int e = 1; e < 4; ++e) if (p[e] > v1) { v1 = p[e]; i1 = e; }
            int i2 = -1; float v2 = -1.f;
            #pragma unroll
            for (int e = 0; e < 4; ++e) if (e != i1 && p[e] > v2) { v2 = p[e]; i2 = e; }
            float gs = v1 + v2;
            float d[4] = {0.f, 0.f, 0.f, 0.f};
            d[i1] = v1 / gs; d[i2] = v2 / gs;
            dsm[px][0] = d[0]; dsm[px][1] = d[1]; dsm[px][2] = d[2]; dsm[px][3] = d[3];
            vals[0]=p[0]; vals[1]=p[1]; vals[2]=p[2]; vals[3]=p[3];
            vals[4]=d[0]>0.f?1.f:0.f; vals[5]=d[1]>0.f?1.f:0.f;
            vals[6]=d[2]>0.f?1.f:0.f; vals[7]=d[3]>0.f?1.f:0.f;
        }
        #pragma unroll
        for (int off = 32; off; off >>= 1)
            #pragma unroll
            for (int i = 0; i < 8; ++i) vals[i] += __shfl_down(vals[i], off);
        if (lane == 0)
            #pragma unroll
            for (int i = 0; i < 8; ++i) sm[wv][i] = vals[i];
    }
    __syncthreads();
    if (tid < 8)
        part[blk * 8 + tid] = sm[0][tid] + sm[1][tid];

    // ---- phase 3: MoE (A from outL, gates from dsm; dbuf hL, 1 barrier/expert) ----
    float g4[4][4];
    #pragma unroll
    for (int e = 0; e < 4; ++e)
        #pragma unroll
        for (int r = 0; r < 4; ++r)
            g4[e][r] = dsm[m0 + kg * 4 + r][e];

    float4v accT[3];
    #pragma unroll
    for (int i = 0; i < 3; ++i) accT[i] = (float4v)0.f;

    for (int e = 0; e < 4; ++e) {
        float4v acc[3];
        #pragma unroll
        for (int i = 0; i < 3; ++i) acc[i] = (float4v)0.f;
        #pragma unroll
        for (int kc = 0; kc < 6; ++kc) {
            short8 a = *(const short8*)(const void*)(&outL[m0 + ln16][kc * 32 + kg * 8]);
            const bf16* wb = w1f + (size_t)e * 36864 + (kc * 12 + wc * 3) * 512 + lane * 8;
            #pragma unroll
            for (int nt = 0; nt < 3; ++nt) {
                short8 bfrag = *(const short8*)(const void*)(wb + nt * 512);
                acc[nt] = __builtin_amdgcn_mfma_f32_16x16x32_bf16(a, bfrag, acc[nt], 0, 0, 0);
            }
        }
        bf16 (*hb)[200] = hL[e & 1];
        #pragma unroll
        for (int nt = 0; nt < 3; ++nt) {
            int c = (wc * 3 + nt) * 16 + ln16;
            float bias = b1[e * 192 + c];
            #pragma unroll
            for (int r = 0; r < 4; ++r)
                hb[m0 + kg * 4 + r][c] = f2b(geluf(acc[nt][r] + bias) * g4[e][r]);
        }
        __syncthreads();
        #pragma unroll
        for (int kc = 0; kc < 6; ++kc) {
            short8 a2 = *(const short8*)(const void*)(&hb[m0 + ln16][kc * 32 + kg * 8]);
            const bf16* wb = w2f + (size_t)e * 36864 + (kc * 12 + wc * 3) * 512 + lane * 8;
            #pragma unroll
            for (int nt = 0; nt < 3; ++nt) {
                short8 bfrag = *(const short8*)(const void*)(wb + nt * 512);
                accT[nt] = __builtin_amdgcn_mfma_f32_16x16x32_bf16(a2, bfrag, accT[nt], 0, 0, 0);
            }
        }
    }
    #pragma unroll
    for (int nt = 0; nt < 3; ++nt) {
        int c = (wc * 3 + nt) * 16 + ln16;
        #pragma unroll
        for (int r = 0; r < 4; ++r) {
            int pix = half * 32 + m0 + kg * 4 + r;
            int tokr = (b * 64 + pab + (pix & 7)) * 64 + npb + (pix >> 3);
            float v = accT[nt][r];
            #pragma unroll
            for (int e = 0; e < 4; ++e) v += g4[e][r] * b2[e * 192 + c];
            stv(&t[(size_t)tokr * 192 + c], v);
        }
    }
}

// ---------------- fused LN2 + MLP via MFMA (256 thr, LDS LN, 64-row) ----------------
template <typename TT>
__global__ __launch_bounds__(256) void k_mlp_mfma(
    TT* __restrict__ t, const float* __restrict__ lg, const float* __restrict__ lb,
    const bf16* __restrict__ w1f, const float* __restrict__ b1,
    const bf16* __restrict__ w2f, const float* __restrict__ b2)
{
    __shared__ __align__(16) bf16 yL[64][200];
    __shared__ __align__(16) bf16 hL[64][200];
    const int rbase = blockIdx.x * 64;
    const int tid = threadIdx.x;
    {
        const int row = tid >> 2, qg = tid & 3;
        float v[48];
        const TT* tr_ = t + (size_t)(rbase + row) * 192 + qg * 48;
        float s = 0.f, sq = 0.f;
        #pragma unroll
        for (int i = 0; i < 12; ++i) {
            float tmp[4]; ld4(tr_ + i * 4, tmp);
            #pragma unroll
            for (int j = 0; j < 4; ++j) { v[i*4+j] = tmp[j]; s += tmp[j]; sq += tmp[j]*tmp[j]; }
        }
        s  += __shfl_xor(s, 1);  s  += __shfl_xor(s, 2);
        sq += __shfl_xor(sq, 1); sq += __shfl_xor(sq, 2);
        float m = s * (1.f/192.f), var = sq * (1.f/192.f) - m*m;
        float rs = rsqrtf(var + 1e-5f);
        #pragma unroll
        for (int i = 0; i < 48; ++i) {
            int d = qg * 48 + i;
            yL[row][d] = f2b((v[i] - m) * rs * lg[d] + lb[d]);
        }
    }
    __syncthreads();
    const int lane = tid & 63, w = tid >> 6;
    const int m0 = w * 16;
    const int kg = lane >> 4, ln16 = lane & 15;
    float4v accT[12];
    #pragma unroll
    for (int i = 0; i < 12; ++i) accT[i] = (float4v)0.f;
    for (int ch = 0; ch < 2; ++ch) {
        float4v acc[12];
        #pragma unroll
        for (int i = 0; i < 12; ++i) acc[i] = (float4v)0.f;
        for (int kc = 0; kc < 6; ++kc) {
            short8 a = *(const short8*)(const void*)(&yL[m0 + ln16][kc * 32 + kg * 8]);
            const bf16* wb = w1f + (size_t)(kc * 24 + ch * 12) * 512 + lane * 8;
            #pragma unroll
            for (int nt = 0; nt < 12; ++nt) {
                short8 bfrag = *(const short8*)(const void*)(wb + nt * 512);
                acc[nt] = __builtin_amdgcn_mfma_f32_16x16x32_bf16(a, bfrag, acc[nt], 0, 0, 0);
            }
        }
        #pragma unroll
        for (int nt = 0; nt < 12; ++nt) {
            int c = nt * 16 + ln16;
            float bias = b1[ch * 192 + c];
            #pragma unroll
            for (int r = 0; r < 4; ++r)
                hL[m0 + kg * 4 + r][c] = f2b(geluf(acc[nt][r] + bias));
        }
        __syncthreads();
        for (int kc = 0; kc < 6; ++kc) {
            short8 a = *(const short8*)(const void*)(&hL[m0 + ln16][kc * 32 + kg * 8]);
            const bf16* wb = w2f + (size_t)((ch * 6 + kc) * 12) * 512 + lane * 8;
            #pragma unroll
            for (int nt = 0; nt < 12; ++nt) {
                short8 bfrag = *(const short8*)(const void*)(wb + nt * 512);
                accT[nt] = __builtin_amdgcn_mfma_f32_16x16x32_bf16(a, bfrag, accT[nt], 0, 0, 0);
            }
        }
        __syncthreads();
    }
    #pragma unroll
    for (int nt = 0; nt < 12; ++nt) {
        int c = nt * 16 + ln16;
        float bias = b2[c];
        #pragma unroll
        for (int r = 0; r < 4; ++r) {
            TT* p = &t[(size_t)(rbase + m0 + kg * 4 + r) * 192 + c];
            stv(p, ldv(p) + accT[nt][r] + bias);
        }
    }
}

// ---------------- fused LN1 + QKV + attention + PROJ, compact-LDS, ILP-paired QKV ----------------
template <typename TT>
__global__ __launch_bounds__(256) void k_attn_mfma(
    TT* __restrict__ t, const float* __restrict__ lg, const float* __restrict__ lb,
    const bf16* __restrict__ qkvwf, const float* __restrict__ qkvb,
    const bf16* __restrict__ pwf, const float* __restrict__ pb)
{
    __shared__ __align__(16) bf16 smem[39424];
    bf16* Qs = smem;              // [64][200], cols h*48+d
    bf16* Ks = smem + 12800;      // [64][200]
    bf16* vT = smem + 25600;      // [4][48][72]
    bf16* pL = smem;              // overlay
    bf16* y2L = smem + 25600;     // overlay, [64][200]
    const int n = blockIdx.x;
    const int tid = threadIdx.x;
    const int w = tid >> 6, lane = tid & 63;
    const int kg = lane >> 4, ln16 = lane & 15;
    const int row = w * 16 + ln16;
    const short8 zfrag = {0, 0, 0, 0, 0, 0, 0, 0};

    // LN in registers, producing A-fragments directly
    short8 afr[6];
    {
        float v[48];
        float s = 0.f, sq = 0.f;
        const TT* tp = t + (size_t)n * 12288 + row * 192 + kg * 8;
        #pragma unroll
        for (int c = 0; c < 6; ++c) {
            float tmp[8]; ld8(tp + c * 32, tmp);
            #pragma unroll
            for (int j = 0; j < 8; ++j) { v[c*8+j] = tmp[j]; s += tmp[j]; sq += tmp[j]*tmp[j]; }
        }
        s  += __shfl_xor(s, 16);  s  += __shfl_xor(s, 32);
        sq += __shfl_xor(sq, 16); sq += __shfl_xor(sq, 32);
        float m = s * (1.f/192.f), var = sq * (1.f/192.f) - m * m;
        float rs = rsqrtf(var + 1e-5f);
        #pragma unroll
        for (int c = 0; c < 6; ++c) {
            float g8[8], b8[8];
            ld8(lg + kg * 8 + c * 32, g8);
            ld8(lb + kg * 8 + c * 32, b8);
            bf16 pk[8];
            #pragma unroll
            for (int j = 0; j < 8; ++j)
                pk[j] = f2b((v[c*8+j] - m) * rs * g8[j] + b8[j]);
            afr[c] = *(const short8*)(const void*)pk;
        }
    }

    const float qscale = 0.14433756729740644f;  // 1/sqrt(48)
    // epilogue scatter for one nt column group
    auto qkv_store = [&](int nt, float4v acc) {
        const int which = nt / 12, h = (nt % 12) / 3, dt = nt % 3;
        const int d = dt * 16 + ln16;
        const float bias = qkvb[nt * 16 + ln16];
        if (which == 0) {
            #pragma unroll
            for (int r = 0; r < 4; ++r)
                Qs[(w * 16 + kg * 4 + r) * 200 + h * 48 + d] = f2b((acc[r] + bias) * qscale);
        } else if (which == 1) {
            #pragma unroll
            for (int r = 0; r < 4; ++r)
                Ks[(w * 16 + kg * 4 + r) * 200 + h * 48 + d] = f2b(acc[r] + bias);
        } else {
            #pragma unroll
            for (int r = 0; r < 4; ++r)
                vT[h * 3456 + d * 72 + (w * 16 + kg * 4 + r)] = f2b(acc[r] + bias);
        }
    };
    // QKV GEMM with paired nt for 2x MFMA ILP (per-chain order unchanged)
    for (int nt2 = 0; nt2 < 18; ++nt2) {
        const int ntA = nt2 * 2, ntB = ntA + 1;
        float4v accA = (float4v)0.f, accB = (float4v)0.f;
        const bf16* wbA = qkvwf + ntA * 512 + lane * 8;
        const bf16* wbB = qkvwf + ntB * 512 + lane * 8;
        #pragma unroll
        for (int kc = 0; kc < 6; ++kc) {
            short8 bfA = *(const short8*)(const void*)(wbA + kc * 36 * 512);
            short8 bfB = *(const short8*)(const void*)(wbB + kc * 36 * 512);
            accA = __builtin_amdgcn_mfma_f32_16x16x32_bf16(afr[kc], bfA, accA, 0, 0, 0);
            accB = __builtin_amdgcn_mfma_f32_16x16x32_bf16(afr[kc], bfB, accB, 0, 0, 0);
        }
        qkv_store(ntA, accA);
        qkv_store(ntB, accB);
    }
    __syncthreads();

    // QK^T for head w: K-dim 48 = kc0 full + kc1 half (kg>=2 slices zero)
    float4v sacc[4][4];
    #pragma unroll
    for (int mt = 0; mt < 4; ++mt)
        #pragma unroll
        for (int nt = 0; nt < 4; ++nt) sacc[mt][nt] = (float4v)0.f;
    #pragma unroll
    for (int kc = 0; kc < 2; ++kc) {
        const bool kv = (kc == 0) || (kg < 2);
        short8 aq[4], bk[4];
        #pragma unroll
        for (int mt = 0; mt < 4; ++mt)
            aq[mt] = kv ? *(const short8*)(const void*)(Qs + (mt * 16 + ln16) * 200 + w * 48 + kc * 32 + kg * 8) : zfrag;
        #pragma unroll
        for (int nt = 0; nt < 4; ++nt)
            bk[nt] = kv ? *(const short8*)(const void*)(Ks + (nt * 16 + ln16) * 200 + w * 48 + kc * 32 + kg * 8) : zfrag;
        #pragma unroll
        for (int mt = 0; mt < 4; ++mt)
            #pragma unroll
            for (int nt = 0; nt < 4; ++nt)
                sacc[mt][nt] = __builtin_amdgcn_mfma_f32_16x16x32_bf16(aq[mt], bk[nt], sacc[mt][nt], 0, 0, 0);
    }
    __syncthreads();   // all Q/K reads done before pL overlay writes

    #pragma unroll
    for (int mt = 0; mt < 4; ++mt) {
        #pragma unroll
        for (int r = 0; r < 4; ++r) {
            float mx = sacc[mt][0][r];
            #pragma unroll
            for (int nt = 1; nt < 4; ++nt) mx = fmaxf(mx, sacc[mt][nt][r]);
            mx = fmaxf(mx, __shfl_xor(mx, 1)); mx = fmaxf(mx, __shfl_xor(mx, 2));
            mx = fmaxf(mx, __shfl_xor(mx, 4)); mx = fmaxf(mx, __shfl_xor(mx, 8));
            float e[4], sum = 0.f;
            #pragma unroll
            for (int nt = 0; nt < 4; ++nt) { e[nt] = expf(sacc[mt][nt][r] - mx); sum += e[nt]; }
            sum += __shfl_xor(sum, 1); sum += __shfl_xor(sum, 2);
            sum += __shfl_xor(sum, 4); sum += __shfl_xor(sum, 8);
            float inv = 1.f / sum;
            #pragma unroll
            for (int nt = 0; nt < 4; ++nt)
                pL[w * 4608 + (mt * 16 + kg * 4 + r) * 72 + nt * 16 + ln16] = f2b(e[nt] * inv);
        }
    }
    float4v oacc[4][3];
    #pragma unroll
    for (int mt = 0; mt < 4; ++mt)
        #pragma unroll
        for (int nt = 0; nt < 3; ++nt) oacc[mt][nt] = (float4v)0.f;
    #pragma unroll
    for (int kc = 0; kc < 2; ++kc) {
        short8 ap[4], bv[3];
        #pragma unroll
        for (int mt = 0; mt < 4; ++mt)
            ap[mt] = *(const short8*)(const void*)(pL + w * 4608 + (mt * 16 + ln16) * 72 + kc * 32 + kg * 8);
        #pragma unroll
        for (int nt = 0; nt < 3; ++nt)
            bv[nt] = *(const short8*)(const void*)(vT + w * 3456 + (nt * 16 + ln16) * 72 + kc * 32 + kg * 8);
        #pragma unroll
        for (int mt = 0; mt < 4; ++mt)
            #pragma unroll
            for (int nt = 0; nt < 3; ++nt)
                oacc[mt][nt] = __builtin_amdgcn_mfma_f32_16x16x32_bf16(ap[mt], bv[nt], oacc[mt][nt], 0, 0, 0);
    }
    // ---- stage y2 in LDS (overlay on vT; all PV reads done) ----
    __syncthreads();
    #pragma unroll
    for (int mt = 0; mt < 4; ++mt)
        #pragma unroll
        for (int nt = 0; nt < 3; ++nt)
            #pragma unroll
            for (int r = 0; r < 4; ++r)
                y2L[(mt * 16 + kg * 4 + r) * 200 + w * 48 + nt * 16 + ln16] = f2b(oacc[mt][nt][r]);
    __syncthreads();
    // ---- proj GEMM: t += y2 @ proj_w + pb ----
    float4v pacc[12];
    #pragma unroll
    for (int i = 0; i < 12; ++i) pacc[i] = (float4v)0.f;
    #pragma unroll
    for (int kc = 0; kc < 6; ++kc) {
        short8 a = *(const short8*)(const void*)(y2L + row * 200 + kc * 32 + kg * 8);
        const bf16* wb = pwf + (kc * 12) * 512 + lane * 8;
        #pragma unroll
        for (int nt = 0; nt < 12; ++nt) {
            short8 bfrag = *(const short8*)(const void*)(wb + nt * 512);
            pacc[nt] = __builtin_amdgcn_mfma_f32_16x16x32_bf16(a, bfrag, pacc[nt], 0, 0, 0);
        }
    }
    #pragma unroll
    for (int nt = 0; nt < 12; ++nt) {
        int c = nt * 16 + ln16;
        float bias = pb[c];
        #pragma unroll
        for (int r = 0; r < 4; ++r) {
            TT* p = &t[((size_t)n * 64 + w * 16 + kg * 4 + r) * 192 + c];
            stv(p, ldv(p) + pacc[nt][r] + bias);
        }
    }
}

// ---------------- fused final LN + unpatchify + 1x1 (192->128) + BN + SiLU via MFMA ----------------
template <typename TT>
__global__ __launch_bounds__(256) void k_unpatch_mfma(
    const TT* __restrict__ t, const float* __restrict__ ng, const float* __restrict__ nb,
    const bf16* __restrict__ wpf, const float* __restrict__ gamma, const float* __restrict__ beta,
    bf16* __restrict__ ph)
{
    __shared__ __align__(16) bf16 outL[64][136];
    const int blk = blockIdx.x;          // = b*64 + pa
    const int b = blk >> 6, pa = blk & 63;
    const int tid = threadIdx.x;
    const int w = tid >> 6, lane = tid & 63;
    const int kg = lane >> 4, ln16 = lane & 15;
    const int row = w * 16 + ln16;       // np index

    short8 afr[6];
    {
        float v[48];
        float s = 0.f, sq = 0.f;
        const TT* tp = t + ((size_t)blk * 64 + row) * 192 + kg * 8;
        #pragma unroll
        for (int c = 0; c < 6; ++c) {
            float tmp[8]; ld8(tp + c * 32, tmp);
            #pragma unroll
            for (int j = 0; j < 8; ++j) { v[c*8+j] = tmp[j]; s += tmp[j]; sq += tmp[j]*tmp[j]; }
        }
        s  += __shfl_xor(s, 16);  s  += __shfl_xor(s, 32);
        sq += __shfl_xor(sq, 16); sq += __shfl_xor(sq, 32);
        float m = s * (1.f/192.f), var = sq * (1.f/192.f) - m * m;
        float rs = rsqrtf(var + 1e-5f);
        #pragma unroll
        for (int c = 0; c < 6; ++c) {
            float g8[8], b8[8];
            ld8(ng + kg * 8 + c * 32, g8);
            ld8(nb + kg * 8 + c * 32, b8);
            bf16 pk[8];
            #pragma unroll
            for (int j = 0; j < 8; ++j)
                pk[j] = f2b((v[c*8+j] - m) * rs * g8[j] + b8[j]);
            afr[c] = *(const short8*)(const void*)pk;
        }
    }

    float4v acc[8];
    #pragma unroll
    for (int i = 0; i < 8; ++i) acc[i] = (float4v)0.f;
    #pragma unroll
    for (int kc = 0; kc < 6; ++kc) {
        const bf16* wb = wpf + (kc * 8) * 512 + lane * 8;
        #pragma unroll
        for (int nt = 0; nt < 8; ++nt) {
            short8 bfrag = *(const short8*)(const void*)(wb + nt * 512);
            acc[nt] = __builtin_amdgcn_mfma_f32_16x16x32_bf16(afr[kc], bfrag, acc[nt], 0, 0, 0);
        }
    }
    #pragma unroll
    for (int nt = 0; nt < 8; ++nt) {
        int c = nt * 16 + ln16;
        float g = gamma[c], be = beta[c];
        #pragma unroll
        for (int r = 0; r < 4; ++r)
            outL[w * 16 + kg * 4 + r][c] = f2b(siluf(g * acc[nt][r] + be));
    }
    __syncthreads();
    for (int idx = tid; idx < 1024; idx += 256) {
        int np = idx >> 4, q = idx & 15;
        int yy = (np >> 3) * 8 + (pa >> 3), xx = (np & 7) * 8 + (pa & 7);
        *(short8*)(void*)(ph + ((size_t)(b * 64 + yy) * 64 + xx) * 128 + q * 8) =
            *(const short8*)(const void*)(&outL[np][q * 8]);
    }
}

// ---------------- moe loss: parallel deterministic reduction over 4096x8 partials ----------------
__global__ __launch_bounds__(256) void k_loss(const float* __restrict__ part, float* __restrict__ out)
{
    __shared__ float red[8][33];
    const int tid = threadIdx.x;
    const int e = tid & 7, g = tid >> 3;   // 32 groups per e
    float s = 0.f;
    for (int i = g; i < 4096; i += 32) s += part[i * 8 + e];
    red[e][g] = s;
    __syncthreads();
    if (tid < 8) {
        float t2 = 0.f;
        for (int g2 = 0; g2 < 32; ++g2) t2 += red[tid][g2];
        red[tid][32] = t2;
    }
    __syncthreads();
    if (tid == 0) {
        float L = 0.f;
        for (int e2 = 0; e2 < 4; ++e2)
            L += (red[e2][32] / 131072.f) * (red[4 + e2][32] / 131072.f);
        out[16777216] = 4.f * L;
    }
}

template <typename TT>
static void run_pipeline(const float* x, const float* w_kxk, const float* bn1_g, const float* bn1_b,
                         const float* w_1x1, const float* gate_w,
                         const float* moe_w1, const float* moe_b1, const float* moe_w2, const float* moe_b2,
                         const float* ln1_g, const float* ln1_b, const float* qkv_w, const float* qkv_b,
                         const float* proj_w, const float* proj_b, const float* ln2_g, const float* ln2_b,
                         const float* fc1_w, const float* fc1_b, const float* fc2_w, const float* fc2_b,
                         const float* nrm_g, const float* nrm_b, const float* w_proj, const float* bn2_g,
                         const float* bn2_b, const float* w_fus, const float* bn3_g, const float* bn3_b,
                         const int* task, float* out, bf16* xh, bf16* tok, TT* t, float* part,
                         bf16* wprep, hipStream_t stream)
{
    // fragment regions inside wprep (prefix == k_prep_all job table)
    bf16* moeW1f = wprep;                 // 147456
    bf16* moeW2f = wprep + 147456;        // 147456
    bf16* fc1f   = wprep + 294912;        // 147456
    bf16* fc2f   = wprep + 442368;        // 147456
    bf16* projWf = wprep + 589824;        // 73728
    bf16* w1x1f  = wprep + 663552;        // 24576
    bf16* convW1f= wprep + 688128;        // 147456
    bf16* convWFf= wprep + 835584;        // 294912
    bf16* qkvWf  = wprep + 1130496;       // 221184
    bf16* wpjf   = wprep + 1351680;       // 24576 -> total 1376256 elems
    hipLaunchKernelGGL(k_prep_all, dim3(5376), dim3(256), 0, stream,
                       moe_w1, moe_w2, fc1_w, fc2_w, proj_w, w_1x1, w_kxk, w_fus, qkv_w, w_proj,
                       wprep);

    bf16* h1h = (bf16*)out;  // d_out used as NHWC bf16 scratch; fully rewritten by final conv
    hipLaunchKernelGGL(k_tohwc, dim3(2048), dim3(256), 0, stream, x, xh);
    hipLaunchKernelGGL(k_conv1_mfma, dim3(2048), dim3(256), 0, stream, xh, convW1f, bn1_g, bn1_b, h1h);
    hipLaunchKernelGGL(k_patchmoe<TT>, dim3(4096), dim3(512), 0, stream,
                       h1h, w1x1f, gate_w, task, moeW1f, moe_b1, moeW2f, moe_b2, t, part);
    for (int l = 0; l < 2; ++l) {
        hipLaunchKernelGGL(k_attn_mfma<TT>, dim3(2048), dim3(256), 0, stream,
                           t, ln1_g + l * 192, ln1_b + l * 192,
                           qkvWf + (size_t)l * 110592, qkv_b + l * 576,
                           projWf + (size_t)l * 36864, proj_b + l * 192);
        hipLaunchKernelGGL(k_mlp_mfma<TT>, dim3(2048), dim3(256), 0, stream,
                           t, ln2_g + l * 192, ln2_b + l * 192,
                           fc1f + (size_t)l * 73728, fc1_b + l * 384,
                           fc2f + (size_t)l * 73728, fc2_b + l * 192);
    }
    bf16* ph = tok;  // tok region used as NHWC p
    hipLaunchKernelGGL(k_unpatch_mfma<TT>, dim3(2048), dim3(256), 0, stream,
                       t, nrm_g, nrm_b, wpjf, bn2_g, bn2_b, ph);
    hipLaunchKernelGGL(k_convf_mfma, dim3(2048), dim3(256), 0, stream,
                       xh, ph, convWFf, bn3_g, bn3_b, out);
    hipLaunchKernelGGL(k_loss, dim3(1), dim3(256), 0, stream, part, out);
}

extern "C" void kernel_launch(void* const* d_in, const int* in_sizes, int n_in,
                              void* d_out, int out_size, void* d_ws, size_t ws_size,
                              hipStream_t stream) {
    const float* x      = (const float*)d_in[0];
    const float* w_kxk  = (const float*)d_in[1];
    const float* bn1_g  = (const float*)d_in[2];
    const float* bn1_b  = (const float*)d_in[3];
    const float* w_1x1  = (const float*)d_in[4];
    const float* gate_w = (const float*)d_in[5];
    const float* moe_w1 = (const float*)d_in[6];
    const float* moe_b1 = (const float*)d_in[7];
    const float* moe_w2 = (const float*)d_in[8];
    const float* moe_b2 = (const float*)d_in[9];
    const float* ln1_g  = (const float*)d_in[10];
    const float* ln1_b  = (const float*)d_in[11];
    const float* qkv_w  = (const float*)d_in[12];
    const float* qkv_b  = (const float*)d_in[13];
    const float* proj_w = (const float*)d_in[14];
    const float* proj_b = (const float*)d_in[15];
    const float* ln2_g  = (const float*)d_in[16];
    const float* ln2_b  = (const float*)d_in[17];
    const float* fc1_w  = (const float*)d_in[18];
    const float* fc1_b  = (const float*)d_in[19];
    const float* fc2_w  = (const float*)d_in[20];
    const float* fc2_b  = (const float*)d_in[21];
    const float* nrm_g  = (const float*)d_in[22];
    const float* nrm_b  = (const float*)d_in[23];
    const float* w_proj = (const float*)d_in[24];
    const float* bn2_g  = (const float*)d_in[25];
    const float* bn2_b  = (const float*)d_in[26];
    const float* w_fus  = (const float*)d_in[27];
    const float* bn3_g  = (const float*)d_in[28];
    const float* bn3_b  = (const float*)d_in[29];
    const int*  task    = (const int*)d_in[30];

    char* wsb = (char*)d_ws;
    const size_t XHB   = 33554432ull;    // NHWC bf16 x
    const size_t TOKB  = 50331648ull;    // ph region
    const size_t T16B  = 50331648ull;    // bf16 residual stream
    const size_t DENB  = 2097152ull;     // part (4096*8 fp32 = 128 KB) lives here
    bf16*  t     = (bf16*)(wsb + XHB + TOKB);
    float* part  = (float*)(wsb + XHB + TOKB + T16B);
    bf16*  wprep = (bf16*)(wsb + XHB + TOKB + T16B + DENB);
    bf16* xh  = (bf16*)wsb;
    bf16* tok = (bf16*)(wsb + XHB);
    float* out = (float*)d_out;

    run_pipeline<bf16>(x, w_kxk, bn1_g, bn1_b, w_1x1, gate_w, moe_w1, moe_b1, moe_w2, moe_b2,
                       ln1_g, ln1_b, qkv_w, qkv_b, proj_w, proj_b, ln2_g, ln2_b,
                       fc1_w, fc1_b, fc2_w, fc2_b, nrm_g, nrm_b, w_proj, bn2_g, bn2_b,
                       w_fus, bn3_g, bn3_b, task, out, xh, tok, t, part, wprep, stream);
}